// Round 4
// baseline (260.023 us; speedup 1.0000x reference)
//
#include <hip/hip_runtime.h>

#define B_TOT 8192
#define NB    8          // batch elements per block
#define NPCS  20

typedef __attribute__((ext_vector_type(8))) __fp16 f16x8;
typedef __attribute__((ext_vector_type(4))) float f32x4;
typedef __attribute__((ext_vector_type(2))) __fp16 fp16x2;

__device__ __forceinline__ unsigned pkmax(unsigned a, unsigned b) {
    unsigned d; asm("v_pk_max_f16 %0, %1, %2" : "=v"(d) : "v"(a), "v"(b)); return d;
}
__device__ __forceinline__ unsigned pkmin(unsigned a, unsigned b) {
    unsigned d; asm("v_pk_min_f16 %0, %1, %2" : "=v"(d) : "v"(a), "v"(b)); return d;
}
// RNE f16 pack via compiler-generated casts (default FP rounding = RNE)
__device__ __forceinline__ unsigned pkrne(float a, float b) {
    fp16x2 h;
    h.x = (__fp16)a;
    h.y = (__fp16)b;
    return __builtin_bit_cast(unsigned, h);
}
// RTZ packed cvt (single instruction) — used for h2/x staging (feeds
// sign-random reductions, so truncation bias cancels statistically)
__device__ __forceinline__ unsigned pkrtz(float a, float b) {
    return __builtin_bit_cast(unsigned, __builtin_amdgcn_cvt_pkrtz(a, b));
}
__device__ __forceinline__ float asf(unsigned u) { return __builtin_bit_cast(float, u); }
__device__ __forceinline__ unsigned asu(float f) { return __builtin_bit_cast(unsigned, f); }
__device__ __forceinline__ fp16x2 ash2(unsigned u) { return __builtin_bit_cast(fp16x2, u); }
__device__ __forceinline__ unsigned asu2(fp16x2 h) { return __builtin_bit_cast(unsigned, h); }

// lane-xor exchange within 16-lane DPP rows; lm constant-folded in unrolled loops.
template<int CTRL>
__device__ __forceinline__ unsigned dppmov(unsigned v) {
    return (unsigned)__builtin_amdgcn_mov_dpp((int)v, CTRL, 0xf, 0xf, true);
}
__device__ __forceinline__ unsigned xlane(unsigned v, int lm) {
    switch (lm) {
    case 1:  return dppmov<0xB1>(v);    // quad_perm [1,0,3,2]  = xor 1
    case 2:  return dppmov<0x4E>(v);    // quad_perm [2,3,0,1]  = xor 2
    case 4:  return (unsigned)__builtin_amdgcn_ds_swizzle((int)v, 0x101F); // xor 4
    default: return dppmov<0x128>(v);   // row_ror:8 == xor 8 within 16-lane row
    }
}
__device__ __forceinline__ float xlanef(float v, int lm) { return asf(xlane(asu(v), lm)); }

// ---------------- d_ws layout (bytes) ----------------
// [0,     32768): W2T f16 [128][128]   w2t[j*128+k] = f16(W2[k][pi(j)])  (pi = bit shuffle)
// [32768, 40960): W3T f16 [32][128]    w3t[c*128+k] = f16(W3[k][c])
// [40960, 57344): wsp f32  [32][128]   precomputed fspool weights
// [57344, 59392): w1d u32 [128][4]     dup-f16 pair (w,w) of W1[k][h]
// [59392, 59904): b1d u32 [128]        dup-f16 pair (b,b) of b1[h]
#define WS_W3T 32768
#define WS_WSP 40960
#define WS_W1D 57344
#define WS_B1D 59392

__device__ __forceinline__ unsigned dup16(float f) {
    unsigned short u = __builtin_bit_cast(unsigned short, (__fp16)f);
    return (unsigned)u * 0x10001u;
}

// pi(j): GEMM2-D-slot -> logical h, chosen so each lane's GEMM2 outputs are
// exactly its GEMM3 B-frag k-elements.  out[6:5]=j[6:5] out[4:3]=j[3:2]
// out[2]=j[4] out[1:0]=j[1:0]
__device__ __forceinline__ int piperm(int j) {
    return (j & 0x60) | ((j & 0x0C) << 1) | ((j & 0x10) >> 2) | (j & 3);
}

__global__ void prep_kernel(const float* __restrict__ W1, const float* __restrict__ b1,
                            const float* __restrict__ W2, const float* __restrict__ W3,
                            const float* __restrict__ pw, void* __restrict__ ws)
{
    const int t = blockIdx.x * 256 + threadIdx.x;
    __fp16* w2t = (__fp16*)ws;
    __fp16* w3t = (__fp16*)((char*)ws + WS_W3T);
    float* wsp  = (float*)((char*)ws + WS_WSP);
    unsigned* w1d = (unsigned*)((char*)ws + WS_W1D);
    unsigned* b1d = (unsigned*)((char*)ws + WS_B1D);
    if (t < 16384) {
        int j = t >> 7, k = t & 127;
        w2t[t] = (__fp16)W2[k * 128 + piperm(j)];
    } else if (t < 20480) {
        int o = t - 16384, c = o >> 7, k = o & 127;
        w3t[o] = (__fp16)W3[k * 32 + c];
    } else if (t < 24576) {
        int o = t - 20480, c = o >> 7, p = o & 127;
        float pos = (float)p * (20.0f / 127.0f);
        int ip = min((int)pos, NPCS);
        float fr = pos - (float)ip;
        int ipb = min(ip + 1, NPCS);
        wsp[o] = (1.0f - fr) * pw[c * 21 + ip] + fr * pw[c * 21 + ipb];
    } else if (t < 24704) {
        int h = t - 24576;
        w1d[h * 4 + 0] = dup16(W1[h]);
        w1d[h * 4 + 1] = dup16(W1[128 + h]);
        w1d[h * 4 + 2] = dup16(W1[256 + h]);
        w1d[h * 4 + 3] = dup16(W1[384 + h]);
        b1d[h] = dup16(b1[h]);
    }
}

// ---------------- LDS layout (bytes, total 44800) ----------------
// [0,     32768): sW2T f16, rows 256 B, chunk phys = ch ^ (row&15)  (xor swizzle)
// [32768, 41216): szp  uint [16][132]  packed-f16 z pairs
// [41216, 43264): sw1d u32 [128][4]  dup-f16 W1
// [43264, 43776): sb1d u32 [128]     dup-f16 b1
// [43776, 44800): spool f32[NB*32]
#define L_SZP  32768
#define L_W1D  41216
#define L_B1D  43264
#define L_POOL 43776

__global__ __launch_bounds__(256, 3) void enc_kernel(
    const float* __restrict__ x,   const float* __restrict__ b1g,
    const float* __restrict__ b2g, const float* __restrict__ b3g,
    const float* __restrict__ eps, const void* __restrict__ ws,
    float* __restrict__ out)
{
    __shared__ __align__(16) char smem[44800];

    const int tid  = threadIdx.x;
    const int wv   = tid >> 6;
    const int lane = tid & 63;
    const int l16  = lane & 15;     // lane-within-group for the sort
    const int quad = lane >> 4;
    const int b0   = blockIdx.x * NB;

    // ---------- stage sW2T (xor-swizzled), w1d+b1d ----------
    {
        const uint4* src = (const uint4*)ws;     // 2048 16B chunks
#pragma unroll
        for (int it = 0; it < 8; ++it) {
            int idx = tid + it * 256;
            int j = idx >> 4, ch = idx & 15;
            *(uint4*)(smem + j * 256 + ((ch ^ (j & 15)) * 16)) = src[idx];
        }
    }
    if (tid < 160) ((uint4*)(smem + L_W1D))[tid] = ((const uint4*)((const char*)ws + WS_W1D))[tid];

    // ---------- hoisted register-resident data (persist across NB elements) ----------
    f16x8 w3f[2][4];                                   // W3T A-frags
    {
        const __fp16* w3t = (const __fp16*)((const char*)ws + WS_W3T);
#pragma unroll
        for (int mt2 = 0; mt2 < 2; ++mt2)
#pragma unroll
            for (int kt = 0; kt < 4; ++kt)
                w3f[mt2][kt] = *(const f16x8*)(w3t + (mt2 * 16 + l16) * 128 + kt * 32 + quad * 8);
    }
    // persistent MFMA bias seeds (C operand of first-kt MFMA; D != C so never clobbered)
    f32x4 b3acc[2];
    {
        float4 t0 = *(const float4*)(b3g + quad * 4);
        float4 t1 = *(const float4*)(b3g + 16 + quad * 4);
        b3acc[0] = (f32x4){t0.x, t0.y, t0.z, t0.w};
        b3acc[1] = (f32x4){t1.x, t1.y, t1.z, t1.w};
    }
    // swapped-GEMM2 D rows = h (pi-ordered): C-seed b2[pi(nt*16+quad*4+r)]
    f32x4 b2acc[8];
#pragma unroll
    for (int nt = 0; nt < 8; ++nt) {
        float4 t4 = *(const float4*)(b2g + (nt >> 1) * 32 + quad * 8 + (nt & 1) * 4);
        b2acc[nt] = (f32x4){t4.x, t4.y, t4.z, t4.w};
    }

    // fspool weights for this lane's pair-row (element-invariant)
    const int pr = wv * 4 + quad;    // packed pair-row: channels 2pr (mu), 2pr+1 (logvar)
    float wE[8], wO[8];
    {
        const float* wsp = (const float*)((const char*)ws + WS_WSP);
        float4 e0 = *(const float4*)(wsp + (2 * pr) * 128 + l16 * 8);
        float4 e1 = *(const float4*)(wsp + (2 * pr) * 128 + l16 * 8 + 4);
        float4 o0 = *(const float4*)(wsp + (2 * pr + 1) * 128 + l16 * 8);
        float4 o1 = *(const float4*)(wsp + (2 * pr + 1) * 128 + l16 * 8 + 4);
        wE[0]=e0.x; wE[1]=e0.y; wE[2]=e0.z; wE[3]=e0.w; wE[4]=e1.x; wE[5]=e1.y; wE[6]=e1.z; wE[7]=e1.w;
        wO[0]=o0.x; wO[1]=o0.y; wO[2]=o0.z; wO[3]=o0.w; wO[4]=o1.x; wO[5]=o1.y; wO[6]=o1.z; wO[7]=o1.w;
    }

    // sort sign-flip masks (per k-stage, lane-dependent, element-invariant)
    const int ib = l16 * 8;
    const unsigned sfl8  = (ib & 8)  ? 0x80008000u : 0u;
    const unsigned sfl16 = (ib & 16) ? 0x80008000u : 0u;
    const unsigned sfl32 = (ib & 32) ? 0x80008000u : 0u;
    const unsigned sfl64 = (ib & 64) ? 0x80008000u : 0u;

    __syncthreads();

    unsigned* szp   = (unsigned*)(smem + L_SZP);       // stride 132
    float*    spool = (float*)(smem + L_POOL);

    // x prefetch: element 0 loaded ahead of the loop
    const float* xptr = x + (size_t)b0 * 512 + (wv * 32 + l16) * 4;
    float4 xv0 = *(const float4*)(xptr);
    float4 xv1 = *(const float4*)(xptr + 64);

    for (int e = 0; e < NB; ++e) {
        // ---------- GEMM1 (packed f16 VALU, K=4): rows (xv0,xv1) share pk halves ----------
        const unsigned xp0 = pkrtz(xv0.x, xv1.x);
        const unsigned xp1 = pkrtz(xv0.y, xv1.y);
        const unsigned xp2 = pkrtz(xv0.z, xv1.z);
        const unsigned xp3 = pkrtz(xv0.w, xv1.w);

        // prefetch next element's x (consumed next iteration; hides HBM latency)
        if (e + 1 < NB) {
            xv0 = *(const float4*)(xptr + (e + 1) * 512);
            xv1 = *(const float4*)(xptr + (e + 1) * 512 + 64);
        }

        union AF { unsigned u[4]; f16x8 v; } a1[2][4];
#pragma unroll
        for (int kt = 0; kt < 4; ++kt) {
            const int k8 = kt * 32 + quad * 8;
#pragma unroll
            for (int jp = 0; jp < 4; ++jp) {
                const int h = k8 + 2 * jp;
                const uint4 wa = *(const uint4*)(smem + L_W1D + h * 16);        // dup pairs for h
                const uint4 wb = *(const uint4*)(smem + L_W1D + h * 16 + 16);   // dup pairs for h+1
                const uint2 bp = *(const uint2*)(smem + L_B1D + h * 4);         // dup bias h, h+1
                fp16x2 accA = ash2(bp.x);
                fp16x2 accB = ash2(bp.y);
                accA = __builtin_elementwise_fma(ash2(xp0), ash2(wa.x), accA);
                accA = __builtin_elementwise_fma(ash2(xp1), ash2(wa.y), accA);
                accA = __builtin_elementwise_fma(ash2(xp2), ash2(wa.z), accA);
                accA = __builtin_elementwise_fma(ash2(xp3), ash2(wa.w), accA);
                accB = __builtin_elementwise_fma(ash2(xp0), ash2(wb.x), accB);
                accB = __builtin_elementwise_fma(ash2(xp1), ash2(wb.y), accB);
                accB = __builtin_elementwise_fma(ash2(xp2), ash2(wb.z), accB);
                accB = __builtin_elementwise_fma(ash2(xp3), ash2(wb.w), accB);
                const unsigned uA = pkmax(asu2(accA), 0u);   // relu, packed
                const unsigned uB = pkmax(asu2(accB), 0u);
                // accA=(rA_h,rB_h), accB=(rA_h1,rB_h1) -> frag mt0=(rA_h,rA_h1), mt1=(rB_h,rB_h1)
                a1[0][kt].u[jp] = __builtin_amdgcn_perm(uA, uB, 0x01000504u);
                a1[1][kt].u[jp] = __builtin_amdgcn_perm(uA, uB, 0x03020706u);
            }
        }

        // ---------- GEMM2 (MFMA f16, SWAPPED): D = W2T-frag . h1-frag, rows=h cols=p ----------
        f32x4 acc2[2][8];
#pragma unroll
        for (int kt = 0; kt < 4; ++kt)
#pragma unroll
            for (int nt = 0; nt < 8; ++nt) {
                const int j = nt * 16 + l16;
                const int phys = (kt * 4 + quad) ^ l16;
                f16x8 wf = *(const f16x8*)(smem + j * 256 + phys * 16);
                if (kt == 0) {
                    acc2[0][nt] = __builtin_amdgcn_mfma_f32_16x16x32_f16(wf, a1[0][0].v, b2acc[nt], 0, 0, 0);
                    acc2[1][nt] = __builtin_amdgcn_mfma_f32_16x16x32_f16(wf, a1[1][0].v, b2acc[nt], 0, 0, 0);
                } else {
                    acc2[0][nt] = __builtin_amdgcn_mfma_f32_16x16x32_f16(wf, a1[0][kt].v, acc2[0][nt], 0, 0, 0);
                    acc2[1][nt] = __builtin_amdgcn_mfma_f32_16x16x32_f16(wf, a1[1][kt].v, acc2[1][nt], 0, 0, 0);
                }
            }

        // ---------- GEMM3: z = W3T @ h2^T (+b3); B-frag = in-register repack (pi magic) ----------
#pragma unroll
        for (int mt = 0; mt < 2; ++mt) {
            // relu + packed-f16: pk[nt] holds h pairs {pi-base, +1} and {+2, +3}
            unsigned pkx[8], pky[8];
#pragma unroll
            for (int nt = 0; nt < 8; ++nt) {
                pkx[nt] = pkmax(pkrtz(acc2[mt][nt][0], acc2[mt][nt][1]), 0u);
                pky[nt] = pkmax(pkrtz(acc2[mt][nt][2], acc2[mt][nt][3]), 0u);
            }
            // a3[kt] k-elems quad*8+{0..7} == pk[2kt],pk[2kt+1] by pi construction
            union A3 { unsigned u[4]; f16x8 v; } a3[4];
#pragma unroll
            for (int kt = 0; kt < 4; ++kt) {
                a3[kt].u[0] = pkx[2 * kt];
                a3[kt].u[1] = pky[2 * kt];
                a3[kt].u[2] = pkx[2 * kt + 1];
                a3[kt].u[3] = pky[2 * kt + 1];
            }

            const int colbase = wv * 32 + mt * 16;
#pragma unroll
            for (int mt2 = 0; mt2 < 2; ++mt2) {
                f32x4 acc = __builtin_amdgcn_mfma_f32_16x16x32_f16(w3f[mt2][0], a3[0].v, b3acc[mt2], 0, 0, 0);
#pragma unroll
                for (int kt = 1; kt < 4; ++kt)
                    acc = __builtin_amdgcn_mfma_f32_16x16x32_f16(w3f[mt2][kt], a3[kt].v, acc, 0, 0, 0);
                // lane holds z rows c = 16*mt2 + 4*quad + r, col p = colbase + l16
                const int prw = 8 * mt2 + 2 * quad;
                szp[prw * 132 + colbase + l16]       = pkrne(acc[0], acc[1]);  // RNE; lo=even c (mu)
                szp[(prw + 1) * 132 + colbase + l16] = pkrne(acc[2], acc[3]);
            }
        }
        __syncthreads();  // all waves' z columns visible

        // ---------- packed-f16 bitonic sort, 8 elems/lane over 16-lane groups ----------
        // group = quad; virtual element index i = l16*8 + r; full sort => input order free
        unsigned v[8];
        {
            const unsigned* zp = szp + pr * 132 + l16 * 8;
            uint4 za = *(const uint4*)zp;
            uint4 zb = *(const uint4*)(zp + 4);
            v[0]=za.x; v[1]=za.y; v[2]=za.z; v[3]=za.w;
            v[4]=zb.x; v[5]=zb.y; v[6]=zb.z; v[7]=zb.w;
        }
#pragma unroll
        for (int k = 2; k <= 128; k <<= 1) {
#pragma unroll
            for (int j = 64; j >= 1; j >>= 1) {
                if (j >= k) continue;
                if (j >= 8) {                       // cross-lane (within 16-lane DPP row)
                    const bool km = ((ib & k) == 0) != ((ib & j) != 0);
                    const int lm = j >> 3;
#pragma unroll
                    for (int r = 0; r < 8; ++r) {
                        unsigned p = xlane(v[r], lm);
                        unsigned mx = pkmax(v[r], p), mn = pkmin(v[r], p);
                        v[r] = km ? mx : mn;
                    }
                } else if (k <= 4) {                // in-lane, static direction
#pragma unroll
                    for (int a = 0; a < 8; ++a) {
                        if (a & j) continue;
                        const int bx = a | j;
                        unsigned mx = pkmax(v[a], v[bx]), mn = pkmin(v[a], v[bx]);
                        if ((a & k) == 0) { v[a] = mx; v[bx] = mn; }
                        else              { v[a] = mn; v[bx] = mx; }
                    }
                } else {                            // k>=8, j<=4: sign-flip -> static descending
                    const unsigned sfl = (k == 8) ? sfl8 : (k == 16) ? sfl16 :
                                         (k == 32) ? sfl32 : (k == 64) ? sfl64 : 0u;
                    if (j == 4 && k != 128) {
#pragma unroll
                        for (int r = 0; r < 8; ++r) v[r] ^= sfl;
                    }
#pragma unroll
                    for (int a = 0; a < 8; ++a) {
                        if (a & j) continue;
                        const int bx = a | j;
                        unsigned mx = pkmax(v[a], v[bx]), mn = pkmin(v[a], v[bx]);
                        v[a] = mx; v[bx] = mn;
                    }
                    if (j == 1 && k != 128) {
#pragma unroll
                        for (int r = 0; r < 8; ++r) v[r] ^= sfl;
                    }
                }
            }
        }

        // ---------- weighted sum + 16-lane group reduction (DPP) ----------
        float sE = 0.f, sO = 0.f;
#pragma unroll
        for (int r = 0; r < 8; ++r) {
            const fp16x2 hv = ash2(v[r]);
            sE = fmaf(wE[r], (float)hv.x, sE);
            sO = fmaf(wO[r], (float)hv.y, sO);
        }
#pragma unroll
        for (int d = 8; d >= 1; d >>= 1) {
            sE += xlanef(sE, d);
            sO += xlanef(sO, d);
        }
        if (l16 == 0) {
            spool[e * 32 + 2 * pr]     = sE;
            spool[e * 32 + 2 * pr + 1] = sO;
        }
        __syncthreads();  // spool ready; protects szp WAR for next element
    }

    // ---------- batched coalesced epilogue (NB*16 == 128) ----------
    if (tid < NB * 16) {
        const int e = tid >> 4, t = tid & 15;
        const float mu = spool[e * 32 + 2 * t];
        const float lv = spool[e * 32 + 2 * t + 1];
        const float ev = eps[(size_t)b0 * 16 + tid];
        const float smp = fmaf(ev, __expf(0.5f * lv), mu);
        out[(size_t)b0 * 16 + tid] = mu;
        out[(size_t)B_TOT * 16 + (size_t)b0 * 16 + tid] = lv;
        out[(size_t)2 * B_TOT * 16 + (size_t)b0 * 16 + tid] = smp;
    }
}

extern "C" void kernel_launch(void* const* d_in, const int* in_sizes, int n_in,
                              void* d_out, int out_size, void* d_ws, size_t ws_size,
                              hipStream_t stream) {
    const float* x   = (const float*)d_in[0];
    const float* W1  = (const float*)d_in[1];
    const float* b1  = (const float*)d_in[2];
    const float* W2  = (const float*)d_in[3];
    const float* b2  = (const float*)d_in[4];
    const float* W3  = (const float*)d_in[5];
    const float* b3  = (const float*)d_in[6];
    const float* pw  = (const float*)d_in[7];
    const float* eps = (const float*)d_in[8];
    float* out = (float*)d_out;

    prep_kernel<<<dim3(97), dim3(256), 0, stream>>>(W1, b1, W2, W3, pw, d_ws);
    enc_kernel<<<dim3(B_TOT / NB), dim3(256), 0, stream>>>(x, b1, b2, b3, eps, d_ws, out);
}

// Round 6
// 157.558 us; speedup vs baseline: 1.6503x; 1.6503x over previous
//
#include <hip/hip_runtime.h>

#define B_TOT 8192
#define NB    16         // batch elements per block
#define NPCS  20

typedef __attribute__((ext_vector_type(8))) __fp16 f16x8;
typedef __attribute__((ext_vector_type(4))) float f32x4;
typedef __attribute__((ext_vector_type(2))) __fp16 fp16x2;

__device__ __forceinline__ unsigned pkmax(unsigned a, unsigned b) {
    unsigned d; asm("v_pk_max_f16 %0, %1, %2" : "=v"(d) : "v"(a), "v"(b)); return d;
}
__device__ __forceinline__ unsigned pkmin(unsigned a, unsigned b) {
    unsigned d; asm("v_pk_min_f16 %0, %1, %2" : "=v"(d) : "v"(a), "v"(b)); return d;
}
// RNE f16 pack via compiler-generated casts (default FP rounding = RNE)
__device__ __forceinline__ unsigned pkrne(float a, float b) {
    fp16x2 h;
    h.x = (__fp16)a;
    h.y = (__fp16)b;
    return __builtin_bit_cast(unsigned, h);
}
// RTZ packed cvt (single instruction) — used for h2/x staging (feeds
// sign-random reductions, so truncation bias cancels statistically)
__device__ __forceinline__ unsigned pkrtz(float a, float b) {
    return __builtin_bit_cast(unsigned, __builtin_amdgcn_cvt_pkrtz(a, b));
}
__device__ __forceinline__ float asf(unsigned u) { return __builtin_bit_cast(float, u); }
__device__ __forceinline__ unsigned asu(float f) { return __builtin_bit_cast(unsigned, f); }
__device__ __forceinline__ fp16x2 ash2(unsigned u) { return __builtin_bit_cast(fp16x2, u); }
__device__ __forceinline__ unsigned asu2(fp16x2 h) { return __builtin_bit_cast(unsigned, h); }

// lane-xor exchange within 16-lane DPP rows; lm constant-folded in unrolled loops.
template<int CTRL>
__device__ __forceinline__ unsigned dppmov(unsigned v) {
    return (unsigned)__builtin_amdgcn_mov_dpp((int)v, CTRL, 0xf, 0xf, true);
}
__device__ __forceinline__ unsigned xlane(unsigned v, int lm) {
    switch (lm) {
    case 1:  return dppmov<0xB1>(v);    // quad_perm [1,0,3,2]  = xor 1
    case 2:  return dppmov<0x4E>(v);    // quad_perm [2,3,0,1]  = xor 2
    case 4:  return (unsigned)__builtin_amdgcn_ds_swizzle((int)v, 0x101F); // xor 4
    default: return dppmov<0x128>(v);   // row_ror:8 == xor 8 within 16-lane row
    }
}
__device__ __forceinline__ float xlanef(float v, int lm) { return asf(xlane(asu(v), lm)); }

// ---------------- d_ws layout (bytes) ----------------
// [0,     32768): W2T f16 [128][128]   w2t[j*128+k] = f16(W2[k][pi(j)])  (pi = bit shuffle)
// [32768, 40960): W3T f16 [32][128]    w3t[c*128+k] = f16(W3[k][c])
// [40960, 57344): wsp f32  [32][128]   precomputed fspool weights
// [57344, 59392): w1d u32 [128][4]     dup-f16 pair (w,w) of W1[k][h]
// [59392, 59904): b1d u32 [128]        dup-f16 pair (b,b) of b1[h]
#define WS_W3T 32768
#define WS_WSP 40960
#define WS_W1D 57344
#define WS_B1D 59392

__device__ __forceinline__ unsigned dup16(float f) {
    unsigned short u = __builtin_bit_cast(unsigned short, (__fp16)f);
    return (unsigned)u * 0x10001u;
}

// pi(j): GEMM2-D-slot -> logical h, chosen so each lane's GEMM2 outputs are
// exactly its GEMM3 B-frag k-elements.  out[6:5]=j[6:5] out[4:3]=j[3:2]
// out[2]=j[4] out[1:0]=j[1:0]
__device__ __forceinline__ int piperm(int j) {
    return (j & 0x60) | ((j & 0x0C) << 1) | ((j & 0x10) >> 2) | (j & 3);
}

__global__ void prep_kernel(const float* __restrict__ W1, const float* __restrict__ b1,
                            const float* __restrict__ W2, const float* __restrict__ W3,
                            const float* __restrict__ pw, void* __restrict__ ws)
{
    const int t = blockIdx.x * 256 + threadIdx.x;
    __fp16* w2t = (__fp16*)ws;
    __fp16* w3t = (__fp16*)((char*)ws + WS_W3T);
    float* wsp  = (float*)((char*)ws + WS_WSP);
    unsigned* w1d = (unsigned*)((char*)ws + WS_W1D);
    unsigned* b1d = (unsigned*)((char*)ws + WS_B1D);
    if (t < 16384) {
        int j = t >> 7, k = t & 127;
        w2t[t] = (__fp16)W2[k * 128 + piperm(j)];
    } else if (t < 20480) {
        int o = t - 16384, c = o >> 7, k = o & 127;
        w3t[o] = (__fp16)W3[k * 32 + c];
    } else if (t < 24576) {
        int o = t - 20480, c = o >> 7, p = o & 127;
        float pos = (float)p * (20.0f / 127.0f);
        int ip = min((int)pos, NPCS);
        float fr = pos - (float)ip;
        int ipb = min(ip + 1, NPCS);
        wsp[o] = (1.0f - fr) * pw[c * 21 + ip] + fr * pw[c * 21 + ipb];
    } else if (t < 24704) {
        int h = t - 24576;
        w1d[h * 4 + 0] = dup16(W1[h]);
        w1d[h * 4 + 1] = dup16(W1[128 + h]);
        w1d[h * 4 + 2] = dup16(W1[256 + h]);
        w1d[h * 4 + 3] = dup16(W1[384 + h]);
        b1d[h] = dup16(b1[h]);
    }
}

// ---------------- LDS layout (bytes, total 45824) ----------------
// [0,     32768): sW2T f16, rows 256 B, chunk phys = ch ^ (row&15)  (xor swizzle)
// [32768, 41216): szp  uint [16][132]  packed-f16 z pairs
// [41216, 43264): sw1d u32 [128][4]  dup-f16 W1
// [43264, 43776): sb1d u32 [128]     dup-f16 b1
// [43776, 45824): spool f32[NB*32] = 2048 B   (NB=16!  R5 bug: was sized for NB=8)
#define L_SZP  32768
#define L_W1D  41216
#define L_B1D  43264
#define L_POOL 43776

__global__ __launch_bounds__(256, 2) void enc_kernel(
    const float* __restrict__ x,   const float* __restrict__ b1g,
    const float* __restrict__ b2g, const float* __restrict__ b3g,
    const float* __restrict__ eps, const void* __restrict__ ws,
    float* __restrict__ out)
{
    __shared__ __align__(16) char smem[45824];

    const int tid  = threadIdx.x;
    const int wv   = tid >> 6;
    const int lane = tid & 63;
    const int l16  = lane & 15;     // lane-within-group for the sort
    const int quad = lane >> 4;
    const int b0   = blockIdx.x * NB;

    // ---------- stage sW2T (xor-swizzled), w1d+b1d ----------
    {
        const uint4* src = (const uint4*)ws;     // 2048 16B chunks
#pragma unroll
        for (int it = 0; it < 8; ++it) {
            int idx = tid + it * 256;
            int j = idx >> 4, ch = idx & 15;
            *(uint4*)(smem + j * 256 + ((ch ^ (j & 15)) * 16)) = src[idx];
        }
    }
    if (tid < 160) ((uint4*)(smem + L_W1D))[tid] = ((const uint4*)((const char*)ws + WS_W1D))[tid];

    // ---------- hoisted register-resident data (persist across NB elements) ----------
    f16x8 w3f[2][4];                                   // W3T A-frags
    {
        const __fp16* w3t = (const __fp16*)((const char*)ws + WS_W3T);
#pragma unroll
        for (int mt2 = 0; mt2 < 2; ++mt2)
#pragma unroll
            for (int kt = 0; kt < 4; ++kt)
                w3f[mt2][kt] = *(const f16x8*)(w3t + (mt2 * 16 + l16) * 128 + kt * 32 + quad * 8);
    }
    // persistent MFMA bias seeds (C operand of first-kt MFMA; D != C so never clobbered)
    f32x4 b3acc[2];
    {
        float4 t0 = *(const float4*)(b3g + quad * 4);
        float4 t1 = *(const float4*)(b3g + 16 + quad * 4);
        b3acc[0] = (f32x4){t0.x, t0.y, t0.z, t0.w};
        b3acc[1] = (f32x4){t1.x, t1.y, t1.z, t1.w};
    }
    // swapped-GEMM2 D rows = h (pi-ordered): C-seed b2[pi(nt*16+quad*4+r)]
    f32x4 b2acc[8];
#pragma unroll
    for (int nt = 0; nt < 8; ++nt) {
        float4 t4 = *(const float4*)(b2g + (nt >> 1) * 32 + quad * 8 + (nt & 1) * 4);
        b2acc[nt] = (f32x4){t4.x, t4.y, t4.z, t4.w};
    }

    // fspool weights for this lane's pair-row (element-invariant)
    const int pr = wv * 4 + quad;    // packed pair-row: channels 2pr (mu), 2pr+1 (logvar)
    float wE[8], wO[8];
    {
        const float* wsp = (const float*)((const char*)ws + WS_WSP);
        float4 e0 = *(const float4*)(wsp + (2 * pr) * 128 + l16 * 8);
        float4 e1 = *(const float4*)(wsp + (2 * pr) * 128 + l16 * 8 + 4);
        float4 o0 = *(const float4*)(wsp + (2 * pr + 1) * 128 + l16 * 8);
        float4 o1 = *(const float4*)(wsp + (2 * pr + 1) * 128 + l16 * 8 + 4);
        wE[0]=e0.x; wE[1]=e0.y; wE[2]=e0.z; wE[3]=e0.w; wE[4]=e1.x; wE[5]=e1.y; wE[6]=e1.z; wE[7]=e1.w;
        wO[0]=o0.x; wO[1]=o0.y; wO[2]=o0.z; wO[3]=o0.w; wO[4]=o1.x; wO[5]=o1.y; wO[6]=o1.z; wO[7]=o1.w;
    }

    // sort sign-flip masks (per k-stage, lane-dependent, element-invariant)
    const int ib = l16 * 8;
    const unsigned sfl8  = (ib & 8)  ? 0x80008000u : 0u;
    const unsigned sfl16 = (ib & 16) ? 0x80008000u : 0u;
    const unsigned sfl32 = (ib & 32) ? 0x80008000u : 0u;
    const unsigned sfl64 = (ib & 64) ? 0x80008000u : 0u;

    __syncthreads();

    unsigned* szp   = (unsigned*)(smem + L_SZP);       // stride 132
    float*    spool = (float*)(smem + L_POOL);

    // x prefetch: element 0 loaded ahead of the loop
    const float* xptr = x + (size_t)b0 * 512 + (wv * 32 + l16) * 4;
    float4 xv0 = *(const float4*)(xptr);
    float4 xv1 = *(const float4*)(xptr + 64);

    for (int e = 0; e < NB; ++e) {
        // ---------- GEMM1 (packed f16 VALU, K=4): rows (xv0,xv1) share pk halves ----------
        const unsigned xp0 = pkrtz(xv0.x, xv1.x);
        const unsigned xp1 = pkrtz(xv0.y, xv1.y);
        const unsigned xp2 = pkrtz(xv0.z, xv1.z);
        const unsigned xp3 = pkrtz(xv0.w, xv1.w);

        // prefetch next element's x (consumed next iteration; hides HBM latency)
        if (e + 1 < NB) {
            xv0 = *(const float4*)(xptr + (e + 1) * 512);
            xv1 = *(const float4*)(xptr + (e + 1) * 512 + 64);
        }

        union AF { unsigned u[4]; f16x8 v; } a1[2][4];
#pragma unroll
        for (int kt = 0; kt < 4; ++kt) {
            const int k8 = kt * 32 + quad * 8;
#pragma unroll
            for (int jp = 0; jp < 4; ++jp) {
                const int h = k8 + 2 * jp;
                const uint4 wa = *(const uint4*)(smem + L_W1D + h * 16);        // dup pairs for h
                const uint4 wb = *(const uint4*)(smem + L_W1D + h * 16 + 16);   // dup pairs for h+1
                const uint2 bp = *(const uint2*)(smem + L_B1D + h * 4);         // dup bias h, h+1
                fp16x2 accA = ash2(bp.x);
                fp16x2 accB = ash2(bp.y);
                accA = __builtin_elementwise_fma(ash2(xp0), ash2(wa.x), accA);
                accA = __builtin_elementwise_fma(ash2(xp1), ash2(wa.y), accA);
                accA = __builtin_elementwise_fma(ash2(xp2), ash2(wa.z), accA);
                accA = __builtin_elementwise_fma(ash2(xp3), ash2(wa.w), accA);
                accB = __builtin_elementwise_fma(ash2(xp0), ash2(wb.x), accB);
                accB = __builtin_elementwise_fma(ash2(xp1), ash2(wb.y), accB);
                accB = __builtin_elementwise_fma(ash2(xp2), ash2(wb.z), accB);
                accB = __builtin_elementwise_fma(ash2(xp3), ash2(wb.w), accB);
                const unsigned uA = pkmax(asu2(accA), 0u);   // relu, packed
                const unsigned uB = pkmax(asu2(accB), 0u);
                // accA=(rA_h,rB_h), accB=(rA_h1,rB_h1) -> frag mt0=(rA_h,rA_h1), mt1=(rB_h,rB_h1)
                a1[0][kt].u[jp] = __builtin_amdgcn_perm(uA, uB, 0x01000504u);
                a1[1][kt].u[jp] = __builtin_amdgcn_perm(uA, uB, 0x03020706u);
            }
        }

        // ---------- GEMM2 (MFMA f16, SWAPPED): D = W2T-frag . h1-frag, rows=h cols=p ----------
        f32x4 acc2[2][8];
#pragma unroll
        for (int kt = 0; kt < 4; ++kt)
#pragma unroll
            for (int nt = 0; nt < 8; ++nt) {
                const int j = nt * 16 + l16;
                const int phys = (kt * 4 + quad) ^ l16;
                f16x8 wf = *(const f16x8*)(smem + j * 256 + phys * 16);
                if (kt == 0) {
                    acc2[0][nt] = __builtin_amdgcn_mfma_f32_16x16x32_f16(wf, a1[0][0].v, b2acc[nt], 0, 0, 0);
                    acc2[1][nt] = __builtin_amdgcn_mfma_f32_16x16x32_f16(wf, a1[1][0].v, b2acc[nt], 0, 0, 0);
                } else {
                    acc2[0][nt] = __builtin_amdgcn_mfma_f32_16x16x32_f16(wf, a1[0][kt].v, acc2[0][nt], 0, 0, 0);
                    acc2[1][nt] = __builtin_amdgcn_mfma_f32_16x16x32_f16(wf, a1[1][kt].v, acc2[1][nt], 0, 0, 0);
                }
            }

        // ---------- GEMM3: z = W3T @ h2^T (+b3); B-frag = in-register repack (pi magic) ----------
#pragma unroll
        for (int mt = 0; mt < 2; ++mt) {
            // relu + packed-f16: pk[nt] holds h pairs {pi-base, +1} and {+2, +3}
            unsigned pkx[8], pky[8];
#pragma unroll
            for (int nt = 0; nt < 8; ++nt) {
                pkx[nt] = pkmax(pkrtz(acc2[mt][nt][0], acc2[mt][nt][1]), 0u);
                pky[nt] = pkmax(pkrtz(acc2[mt][nt][2], acc2[mt][nt][3]), 0u);
            }
            // a3[kt] k-elems quad*8+{0..7} == pk[2kt],pk[2kt+1] by pi construction
            union A3 { unsigned u[4]; f16x8 v; } a3[4];
#pragma unroll
            for (int kt = 0; kt < 4; ++kt) {
                a3[kt].u[0] = pkx[2 * kt];
                a3[kt].u[1] = pky[2 * kt];
                a3[kt].u[2] = pkx[2 * kt + 1];
                a3[kt].u[3] = pky[2 * kt + 1];
            }

            const int colbase = wv * 32 + mt * 16;
#pragma unroll
            for (int mt2 = 0; mt2 < 2; ++mt2) {
                f32x4 acc = __builtin_amdgcn_mfma_f32_16x16x32_f16(w3f[mt2][0], a3[0].v, b3acc[mt2], 0, 0, 0);
#pragma unroll
                for (int kt = 1; kt < 4; ++kt)
                    acc = __builtin_amdgcn_mfma_f32_16x16x32_f16(w3f[mt2][kt], a3[kt].v, acc, 0, 0, 0);
                // lane holds z rows c = 16*mt2 + 4*quad + r, col p = colbase + l16
                const int prw = 8 * mt2 + 2 * quad;
                szp[prw * 132 + colbase + l16]       = pkrne(acc[0], acc[1]);  // RNE; lo=even c (mu)
                szp[(prw + 1) * 132 + colbase + l16] = pkrne(acc[2], acc[3]);
            }
        }
        __syncthreads();  // all waves' z columns visible

        // ---------- packed-f16 bitonic sort, 8 elems/lane over 16-lane groups ----------
        // group = quad; virtual element index i = l16*8 + r; full sort => input order free
        unsigned v[8];
        {
            const unsigned* zp = szp + pr * 132 + l16 * 8;
            uint4 za = *(const uint4*)zp;
            uint4 zb = *(const uint4*)(zp + 4);
            v[0]=za.x; v[1]=za.y; v[2]=za.z; v[3]=za.w;
            v[4]=zb.x; v[5]=zb.y; v[6]=zb.z; v[7]=zb.w;
        }
#pragma unroll
        for (int k = 2; k <= 128; k <<= 1) {
#pragma unroll
            for (int j = 64; j >= 1; j >>= 1) {
                if (j >= k) continue;
                if (j >= 8) {                       // cross-lane (within 16-lane DPP row)
                    const bool km = ((ib & k) == 0) != ((ib & j) != 0);
                    const int lm = j >> 3;
#pragma unroll
                    for (int r = 0; r < 8; ++r) {
                        unsigned p = xlane(v[r], lm);
                        unsigned mx = pkmax(v[r], p), mn = pkmin(v[r], p);
                        v[r] = km ? mx : mn;
                    }
                } else if (k <= 4) {                // in-lane, static direction
#pragma unroll
                    for (int a = 0; a < 8; ++a) {
                        if (a & j) continue;
                        const int bx = a | j;
                        unsigned mx = pkmax(v[a], v[bx]), mn = pkmin(v[a], v[bx]);
                        if ((a & k) == 0) { v[a] = mx; v[bx] = mn; }
                        else              { v[a] = mn; v[bx] = mx; }
                    }
                } else {                            // k>=8, j<=4: sign-flip -> static descending
                    const unsigned sfl = (k == 8) ? sfl8 : (k == 16) ? sfl16 :
                                         (k == 32) ? sfl32 : (k == 64) ? sfl64 : 0u;
                    if (j == 4 && k != 128) {
#pragma unroll
                        for (int r = 0; r < 8; ++r) v[r] ^= sfl;
                    }
#pragma unroll
                    for (int a = 0; a < 8; ++a) {
                        if (a & j) continue;
                        const int bx = a | j;
                        unsigned mx = pkmax(v[a], v[bx]), mn = pkmin(v[a], v[bx]);
                        v[a] = mx; v[bx] = mn;
                    }
                    if (j == 1 && k != 128) {
#pragma unroll
                        for (int r = 0; r < 8; ++r) v[r] ^= sfl;
                    }
                }
            }
        }

        // ---------- weighted sum + 16-lane group reduction (DPP) ----------
        float sE = 0.f, sO = 0.f;
#pragma unroll
        for (int r = 0; r < 8; ++r) {
            const fp16x2 hv = ash2(v[r]);
            sE = fmaf(wE[r], (float)hv.x, sE);
            sO = fmaf(wO[r], (float)hv.y, sO);
        }
#pragma unroll
        for (int d = 8; d >= 1; d >>= 1) {
            sE += xlanef(sE, d);
            sO += xlanef(sO, d);
        }
        if (l16 == 0) {
            spool[e * 32 + 2 * pr]     = sE;
            spool[e * 32 + 2 * pr + 1] = sO;
        }
        __syncthreads();  // spool ready; protects szp WAR for next element
    }

    // ---------- batched coalesced epilogue (NB*16 == 256) ----------
    {
        const int e = tid >> 4, t = tid & 15;
        const float mu = spool[e * 32 + 2 * t];
        const float lv = spool[e * 32 + 2 * t + 1];
        const float ev = eps[(size_t)b0 * 16 + tid];
        const float smp = fmaf(ev, __expf(0.5f * lv), mu);
        out[(size_t)b0 * 16 + tid] = mu;
        out[(size_t)B_TOT * 16 + (size_t)b0 * 16 + tid] = lv;
        out[(size_t)2 * B_TOT * 16 + (size_t)b0 * 16 + tid] = smp;
    }
}

extern "C" void kernel_launch(void* const* d_in, const int* in_sizes, int n_in,
                              void* d_out, int out_size, void* d_ws, size_t ws_size,
                              hipStream_t stream) {
    const float* x   = (const float*)d_in[0];
    const float* W1  = (const float*)d_in[1];
    const float* b1  = (const float*)d_in[2];
    const float* W2  = (const float*)d_in[3];
    const float* b2  = (const float*)d_in[4];
    const float* W3  = (const float*)d_in[5];
    const float* b3  = (const float*)d_in[6];
    const float* pw  = (const float*)d_in[7];
    const float* eps = (const float*)d_in[8];
    float* out = (float*)d_out;

    prep_kernel<<<dim3(97), dim3(256), 0, stream>>>(W1, b1, W2, W3, pw, d_ws);
    enc_kernel<<<dim3(B_TOT / NB), dim3(256), 0, stream>>>(x, b1, b2, b3, eps, d_ws, out);
}

// Round 7
// 156.329 us; speedup vs baseline: 1.6633x; 1.0079x over previous
//
#include <hip/hip_runtime.h>

#define B_TOT 8192
#define NB    8          // batch elements per block (1024 blocks -> 3 resident/CU)
#define NPCS  20

typedef __attribute__((ext_vector_type(8))) __fp16 f16x8;
typedef __attribute__((ext_vector_type(4))) float f32x4;
typedef __attribute__((ext_vector_type(2))) __fp16 fp16x2;

__device__ __forceinline__ unsigned pkmax(unsigned a, unsigned b) {
    unsigned d; asm("v_pk_max_f16 %0, %1, %2" : "=v"(d) : "v"(a), "v"(b)); return d;
}
__device__ __forceinline__ unsigned pkmin(unsigned a, unsigned b) {
    unsigned d; asm("v_pk_min_f16 %0, %1, %2" : "=v"(d) : "v"(a), "v"(b)); return d;
}
// RNE f16 pack via compiler-generated casts (default FP rounding = RNE)
__device__ __forceinline__ unsigned pkrne(float a, float b) {
    fp16x2 h;
    h.x = (__fp16)a;
    h.y = (__fp16)b;
    return __builtin_bit_cast(unsigned, h);
}
// RTZ packed cvt (single instruction) — used for h2/x staging (feeds
// sign-random reductions, so truncation bias cancels statistically)
__device__ __forceinline__ unsigned pkrtz(float a, float b) {
    return __builtin_bit_cast(unsigned, __builtin_amdgcn_cvt_pkrtz(a, b));
}
__device__ __forceinline__ float asf(unsigned u) { return __builtin_bit_cast(float, u); }
__device__ __forceinline__ unsigned asu(float f) { return __builtin_bit_cast(unsigned, f); }
__device__ __forceinline__ fp16x2 ash2(unsigned u) { return __builtin_bit_cast(fp16x2, u); }
__device__ __forceinline__ unsigned asu2(fp16x2 h) { return __builtin_bit_cast(unsigned, h); }

// lane-xor exchange within 16-lane DPP rows; lm constant-folded in unrolled loops.
template<int CTRL>
__device__ __forceinline__ unsigned dppmov(unsigned v) {
    return (unsigned)__builtin_amdgcn_mov_dpp((int)v, CTRL, 0xf, 0xf, true);
}
__device__ __forceinline__ unsigned xlane(unsigned v, int lm) {
    switch (lm) {
    case 1:  return dppmov<0xB1>(v);    // quad_perm [1,0,3,2]  = xor 1
    case 2:  return dppmov<0x4E>(v);    // quad_perm [2,3,0,1]  = xor 2
    case 4:  return (unsigned)__builtin_amdgcn_ds_swizzle((int)v, 0x101F); // xor 4
    default: return dppmov<0x128>(v);   // row_ror:8 == xor 8 within 16-lane row
    }
}
__device__ __forceinline__ float xlanef(float v, int lm) { return asf(xlane(asu(v), lm)); }

// ---------------- d_ws layout (bytes) ----------------
// [0,     32768): W2T f16 [128][128]   w2t[j*128+k] = f16(W2[k][pi(j)])  (pi = bit shuffle)
// [32768, 40960): W3T f16 [32][128]    w3t[c*128+k] = f16(W3[k][c])
// [40960, 57344): wsp f32  [32][128]   precomputed fspool weights
// [57344, 59392): w1d u32 [128][4]     dup-f16 pair (w,w) of W1[k][h]
// [59392, 59904): b1d u32 [128]        dup-f16 pair (b,b) of b1[h]
#define WS_W3T 32768
#define WS_WSP 40960
#define WS_W1D 57344
#define WS_B1D 59392

__device__ __forceinline__ unsigned dup16(float f) {
    unsigned short u = __builtin_bit_cast(unsigned short, (__fp16)f);
    return (unsigned)u * 0x10001u;
}

// pi(j): GEMM2-D-slot -> logical h, chosen so each lane's GEMM2 outputs are
// exactly its GEMM3 B-frag k-elements.  out[6:5]=j[6:5] out[4:3]=j[3:2]
// out[2]=j[4] out[1:0]=j[1:0]
__device__ __forceinline__ int piperm(int j) {
    return (j & 0x60) | ((j & 0x0C) << 1) | ((j & 0x10) >> 2) | (j & 3);
}

__global__ void prep_kernel(const float* __restrict__ W1, const float* __restrict__ b1,
                            const float* __restrict__ W2, const float* __restrict__ W3,
                            const float* __restrict__ pw, void* __restrict__ ws)
{
    const int t = blockIdx.x * 256 + threadIdx.x;
    __fp16* w2t = (__fp16*)ws;
    __fp16* w3t = (__fp16*)((char*)ws + WS_W3T);
    float* wsp  = (float*)((char*)ws + WS_WSP);
    unsigned* w1d = (unsigned*)((char*)ws + WS_W1D);
    unsigned* b1d = (unsigned*)((char*)ws + WS_B1D);
    if (t < 16384) {
        int j = t >> 7, k = t & 127;
        w2t[t] = (__fp16)W2[k * 128 + piperm(j)];
    } else if (t < 20480) {
        int o = t - 16384, c = o >> 7, k = o & 127;
        w3t[o] = (__fp16)W3[k * 32 + c];
    } else if (t < 24576) {
        int o = t - 20480, c = o >> 7, p = o & 127;
        float pos = (float)p * (20.0f / 127.0f);
        int ip = min((int)pos, NPCS);
        float fr = pos - (float)ip;
        int ipb = min(ip + 1, NPCS);
        wsp[o] = (1.0f - fr) * pw[c * 21 + ip] + fr * pw[c * 21 + ipb];
    } else if (t < 24704) {
        int h = t - 24576;
        w1d[h * 4 + 0] = dup16(W1[h]);
        w1d[h * 4 + 1] = dup16(W1[128 + h]);
        w1d[h * 4 + 2] = dup16(W1[256 + h]);
        w1d[h * 4 + 3] = dup16(W1[384 + h]);
        b1d[h] = dup16(b1[h]);
    }
}

// ---------------- LDS layout (bytes, total 44800) ----------------
// [0,     32768): sW2T f16, rows 256 B, chunk phys = ch ^ (row&15)  (xor swizzle)
// [32768, 41216): szp  uint [16][132]  packed-f16 z pairs
// [41216, 43264): sw1d u32 [128][4]  dup-f16 W1
// [43264, 43776): sb1d u32 [128]     dup-f16 b1
// [43776, 44800): spool f32[NB*32] = 1024 B  (NB=8)
#define L_SZP  32768
#define L_W1D  41216
#define L_B1D  43264
#define L_POOL 43776

__global__ __launch_bounds__(256, 2) void enc_kernel(
    const float* __restrict__ x,   const float* __restrict__ b1g,
    const float* __restrict__ b2g, const float* __restrict__ b3g,
    const float* __restrict__ eps, const void* __restrict__ ws,
    float* __restrict__ out)
{
    __shared__ __align__(16) char smem[44800];

    const int tid  = threadIdx.x;
    const int wv   = tid >> 6;
    const int lane = tid & 63;
    const int l16  = lane & 15;     // lane-within-group for the sort
    const int quad = lane >> 4;
    const int b0   = blockIdx.x * NB;

    // ---------- stage sW2T (xor-swizzled), w1d+b1d ----------
    {
        const uint4* src = (const uint4*)ws;     // 2048 16B chunks
#pragma unroll
        for (int it = 0; it < 8; ++it) {
            int idx = tid + it * 256;
            int j = idx >> 4, ch = idx & 15;
            *(uint4*)(smem + j * 256 + ((ch ^ (j & 15)) * 16)) = src[idx];
        }
    }
    if (tid < 160) ((uint4*)(smem + L_W1D))[tid] = ((const uint4*)((const char*)ws + WS_W1D))[tid];

    // ---------- hoisted register-resident data (persist across NB elements) ----------
    f16x8 w3f[2][4];                                   // W3T A-frags
    {
        const __fp16* w3t = (const __fp16*)((const char*)ws + WS_W3T);
#pragma unroll
        for (int mt2 = 0; mt2 < 2; ++mt2)
#pragma unroll
            for (int kt = 0; kt < 4; ++kt)
                w3f[mt2][kt] = *(const f16x8*)(w3t + (mt2 * 16 + l16) * 128 + kt * 32 + quad * 8);
    }
    // persistent MFMA bias seeds (C operand of first-kt MFMA; D != C so never clobbered)
    f32x4 b3acc[2];
    {
        float4 t0 = *(const float4*)(b3g + quad * 4);
        float4 t1 = *(const float4*)(b3g + 16 + quad * 4);
        b3acc[0] = (f32x4){t0.x, t0.y, t0.z, t0.w};
        b3acc[1] = (f32x4){t1.x, t1.y, t1.z, t1.w};
    }
    // swapped-GEMM2 D rows = h (pi-ordered): C-seed b2[pi(nt*16+quad*4+r)]
    f32x4 b2acc[8];
#pragma unroll
    for (int nt = 0; nt < 8; ++nt) {
        float4 t4 = *(const float4*)(b2g + (nt >> 1) * 32 + quad * 8 + (nt & 1) * 4);
        b2acc[nt] = (f32x4){t4.x, t4.y, t4.z, t4.w};
    }

    // fspool weights for this lane's pair-row (element-invariant)
    const int pr = wv * 4 + quad;    // packed pair-row: channels 2pr (mu), 2pr+1 (logvar)
    float wE[8], wO[8];
    {
        const float* wsp = (const float*)((const char*)ws + WS_WSP);
        float4 e0 = *(const float4*)(wsp + (2 * pr) * 128 + l16 * 8);
        float4 e1 = *(const float4*)(wsp + (2 * pr) * 128 + l16 * 8 + 4);
        float4 o0 = *(const float4*)(wsp + (2 * pr + 1) * 128 + l16 * 8);
        float4 o1 = *(const float4*)(wsp + (2 * pr + 1) * 128 + l16 * 8 + 4);
        wE[0]=e0.x; wE[1]=e0.y; wE[2]=e0.z; wE[3]=e0.w; wE[4]=e1.x; wE[5]=e1.y; wE[6]=e1.z; wE[7]=e1.w;
        wO[0]=o0.x; wO[1]=o0.y; wO[2]=o0.z; wO[3]=o0.w; wO[4]=o1.x; wO[5]=o1.y; wO[6]=o1.z; wO[7]=o1.w;
    }

    // sort sign-flip masks (per k-stage, lane-dependent, element-invariant)
    const int ib = l16 * 8;
    const unsigned sfl8  = (ib & 8)  ? 0x80008000u : 0u;
    const unsigned sfl16 = (ib & 16) ? 0x80008000u : 0u;
    const unsigned sfl32 = (ib & 32) ? 0x80008000u : 0u;
    const unsigned sfl64 = (ib & 64) ? 0x80008000u : 0u;

    __syncthreads();

    unsigned* szp   = (unsigned*)(smem + L_SZP);       // stride 132
    float*    spool = (float*)(smem + L_POOL);

    // x prefetch: element 0 loaded ahead of the loop
    const float* xptr = x + (size_t)b0 * 512 + (wv * 32 + l16) * 4;
    float4 xv0 = *(const float4*)(xptr);
    float4 xv1 = *(const float4*)(xptr + 64);

    for (int e = 0; e < NB; ++e) {
        // ---------- GEMM1 (packed f16 VALU, K=4): rows (xv0,xv1) share pk halves ----------
        const unsigned xp0 = pkrtz(xv0.x, xv1.x);
        const unsigned xp1 = pkrtz(xv0.y, xv1.y);
        const unsigned xp2 = pkrtz(xv0.z, xv1.z);
        const unsigned xp3 = pkrtz(xv0.w, xv1.w);

        // prefetch next element's x (consumed next iteration; hides HBM latency)
        if (e + 1 < NB) {
            xv0 = *(const float4*)(xptr + (e + 1) * 512);
            xv1 = *(const float4*)(xptr + (e + 1) * 512 + 64);
        }

        union AF { unsigned u[4]; f16x8 v; } a1[2][4];
#pragma unroll
        for (int kt = 0; kt < 4; ++kt) {
            const int k8 = kt * 32 + quad * 8;
#pragma unroll
            for (int jp = 0; jp < 4; ++jp) {
                const int h = k8 + 2 * jp;
                const uint4 wa = *(const uint4*)(smem + L_W1D + h * 16);        // dup pairs for h
                const uint4 wb = *(const uint4*)(smem + L_W1D + h * 16 + 16);   // dup pairs for h+1
                const uint2 bp = *(const uint2*)(smem + L_B1D + h * 4);         // dup bias h, h+1
                fp16x2 accA = ash2(bp.x);
                fp16x2 accB = ash2(bp.y);
                accA = __builtin_elementwise_fma(ash2(xp0), ash2(wa.x), accA);
                accA = __builtin_elementwise_fma(ash2(xp1), ash2(wa.y), accA);
                accA = __builtin_elementwise_fma(ash2(xp2), ash2(wa.z), accA);
                accA = __builtin_elementwise_fma(ash2(xp3), ash2(wa.w), accA);
                accB = __builtin_elementwise_fma(ash2(xp0), ash2(wb.x), accB);
                accB = __builtin_elementwise_fma(ash2(xp1), ash2(wb.y), accB);
                accB = __builtin_elementwise_fma(ash2(xp2), ash2(wb.z), accB);
                accB = __builtin_elementwise_fma(ash2(xp3), ash2(wb.w), accB);
                const unsigned uA = pkmax(asu2(accA), 0u);   // relu, packed
                const unsigned uB = pkmax(asu2(accB), 0u);
                // accA=(rA_h,rB_h), accB=(rA_h1,rB_h1) -> frag mt0=(rA_h,rA_h1), mt1=(rB_h,rB_h1)
                a1[0][kt].u[jp] = __builtin_amdgcn_perm(uA, uB, 0x01000504u);
                a1[1][kt].u[jp] = __builtin_amdgcn_perm(uA, uB, 0x03020706u);
            }
        }

        // ---------- GEMM2 (MFMA f16, SWAPPED): D = W2T-frag . h1-frag, rows=h cols=p ----------
        f32x4 acc2[2][8];
#pragma unroll
        for (int kt = 0; kt < 4; ++kt)
#pragma unroll
            for (int nt = 0; nt < 8; ++nt) {
                const int j = nt * 16 + l16;
                const int phys = (kt * 4 + quad) ^ l16;
                f16x8 wf = *(const f16x8*)(smem + j * 256 + phys * 16);
                if (kt == 0) {
                    acc2[0][nt] = __builtin_amdgcn_mfma_f32_16x16x32_f16(wf, a1[0][0].v, b2acc[nt], 0, 0, 0);
                    acc2[1][nt] = __builtin_amdgcn_mfma_f32_16x16x32_f16(wf, a1[1][0].v, b2acc[nt], 0, 0, 0);
                } else {
                    acc2[0][nt] = __builtin_amdgcn_mfma_f32_16x16x32_f16(wf, a1[0][kt].v, acc2[0][nt], 0, 0, 0);
                    acc2[1][nt] = __builtin_amdgcn_mfma_f32_16x16x32_f16(wf, a1[1][kt].v, acc2[1][nt], 0, 0, 0);
                }
            }

        // ---------- GEMM3: z = W3T @ h2^T (+b3); B-frag = in-register repack (pi magic) ----------
#pragma unroll
        for (int mt = 0; mt < 2; ++mt) {
            // relu + packed-f16: pk[nt] holds h pairs {pi-base, +1} and {+2, +3}
            unsigned pkx[8], pky[8];
#pragma unroll
            for (int nt = 0; nt < 8; ++nt) {
                pkx[nt] = pkmax(pkrtz(acc2[mt][nt][0], acc2[mt][nt][1]), 0u);
                pky[nt] = pkmax(pkrtz(acc2[mt][nt][2], acc2[mt][nt][3]), 0u);
            }
            // a3[kt] k-elems quad*8+{0..7} == pk[2kt],pk[2kt+1] by pi construction
            union A3 { unsigned u[4]; f16x8 v; } a3[4];
#pragma unroll
            for (int kt = 0; kt < 4; ++kt) {
                a3[kt].u[0] = pkx[2 * kt];
                a3[kt].u[1] = pky[2 * kt];
                a3[kt].u[2] = pkx[2 * kt + 1];
                a3[kt].u[3] = pky[2 * kt + 1];
            }

            const int colbase = wv * 32 + mt * 16;
#pragma unroll
            for (int mt2 = 0; mt2 < 2; ++mt2) {
                f32x4 acc = __builtin_amdgcn_mfma_f32_16x16x32_f16(w3f[mt2][0], a3[0].v, b3acc[mt2], 0, 0, 0);
#pragma unroll
                for (int kt = 1; kt < 4; ++kt)
                    acc = __builtin_amdgcn_mfma_f32_16x16x32_f16(w3f[mt2][kt], a3[kt].v, acc, 0, 0, 0);
                // lane holds z rows c = 16*mt2 + 4*quad + r, col p = colbase + l16
                const int prw = 8 * mt2 + 2 * quad;
                szp[prw * 132 + colbase + l16]       = pkrne(acc[0], acc[1]);  // RNE; lo=even c (mu)
                szp[(prw + 1) * 132 + colbase + l16] = pkrne(acc[2], acc[3]);
            }
        }
        __syncthreads();  // all waves' z columns visible

        // ---------- packed-f16 bitonic sort, 8 elems/lane over 16-lane groups ----------
        // group = quad; virtual element index i = l16*8 + r; full sort => input order free
        unsigned v[8];
        {
            const unsigned* zp = szp + pr * 132 + l16 * 8;
            uint4 za = *(const uint4*)zp;
            uint4 zb = *(const uint4*)(zp + 4);
            v[0]=za.x; v[1]=za.y; v[2]=za.z; v[3]=za.w;
            v[4]=zb.x; v[5]=zb.y; v[6]=zb.z; v[7]=zb.w;
        }
#pragma unroll
        for (int k = 2; k <= 128; k <<= 1) {
#pragma unroll
            for (int j = 64; j >= 1; j >>= 1) {
                if (j >= k) continue;
                if (j >= 8) {                       // cross-lane (within 16-lane DPP row)
                    const bool km = ((ib & k) == 0) != ((ib & j) != 0);
                    const int lm = j >> 3;
#pragma unroll
                    for (int r = 0; r < 8; ++r) {
                        unsigned p = xlane(v[r], lm);
                        unsigned mx = pkmax(v[r], p), mn = pkmin(v[r], p);
                        v[r] = km ? mx : mn;
                    }
                } else if (k <= 4) {                // in-lane, static direction
#pragma unroll
                    for (int a = 0; a < 8; ++a) {
                        if (a & j) continue;
                        const int bx = a | j;
                        unsigned mx = pkmax(v[a], v[bx]), mn = pkmin(v[a], v[bx]);
                        if ((a & k) == 0) { v[a] = mx; v[bx] = mn; }
                        else              { v[a] = mn; v[bx] = mx; }
                    }
                } else {                            // k>=8, j<=4: sign-flip -> static descending
                    const unsigned sfl = (k == 8) ? sfl8 : (k == 16) ? sfl16 :
                                         (k == 32) ? sfl32 : (k == 64) ? sfl64 : 0u;
                    if (j == 4 && k != 128) {
#pragma unroll
                        for (int r = 0; r < 8; ++r) v[r] ^= sfl;
                    }
#pragma unroll
                    for (int a = 0; a < 8; ++a) {
                        if (a & j) continue;
                        const int bx = a | j;
                        unsigned mx = pkmax(v[a], v[bx]), mn = pkmin(v[a], v[bx]);
                        v[a] = mx; v[bx] = mn;
                    }
                    if (j == 1 && k != 128) {
#pragma unroll
                        for (int r = 0; r < 8; ++r) v[r] ^= sfl;
                    }
                }
            }
        }

        // ---------- weighted sum + 16-lane group reduction (DPP) ----------
        float sE = 0.f, sO = 0.f;
#pragma unroll
        for (int r = 0; r < 8; ++r) {
            const fp16x2 hv = ash2(v[r]);
            sE = fmaf(wE[r], (float)hv.x, sE);
            sO = fmaf(wO[r], (float)hv.y, sO);
        }
#pragma unroll
        for (int d = 8; d >= 1; d >>= 1) {
            sE += xlanef(sE, d);
            sO += xlanef(sO, d);
        }
        if (l16 == 0) {
            spool[e * 32 + 2 * pr]     = sE;
            spool[e * 32 + 2 * pr + 1] = sO;
        }
        __syncthreads();  // spool ready; protects szp WAR for next element
    }

    // ---------- batched coalesced epilogue (NB*16 == 128) ----------
    if (tid < NB * 16) {
        const int e = tid >> 4, t = tid & 15;
        const float mu = spool[e * 32 + 2 * t];
        const float lv = spool[e * 32 + 2 * t + 1];
        const float ev = eps[(size_t)b0 * 16 + tid];
        const float smp = fmaf(ev, __expf(0.5f * lv), mu);
        out[(size_t)b0 * 16 + tid] = mu;
        out[(size_t)B_TOT * 16 + (size_t)b0 * 16 + tid] = lv;
        out[(size_t)2 * B_TOT * 16 + (size_t)b0 * 16 + tid] = smp;
    }
}

extern "C" void kernel_launch(void* const* d_in, const int* in_sizes, int n_in,
                              void* d_out, int out_size, void* d_ws, size_t ws_size,
                              hipStream_t stream) {
    const float* x   = (const float*)d_in[0];
    const float* W1  = (const float*)d_in[1];
    const float* b1  = (const float*)d_in[2];
    const float* W2  = (const float*)d_in[3];
    const float* b2  = (const float*)d_in[4];
    const float* W3  = (const float*)d_in[5];
    const float* b3  = (const float*)d_in[6];
    const float* pw  = (const float*)d_in[7];
    const float* eps = (const float*)d_in[8];
    float* out = (float*)d_out;

    prep_kernel<<<dim3(97), dim3(256), 0, stream>>>(W1, b1, W2, W3, pw, d_ws);
    enc_kernel<<<dim3(B_TOT / NB), dim3(256), 0, stream>>>(x, b1, b2, b3, eps, d_ws, out);
}

// Round 8
// 144.948 us; speedup vs baseline: 1.7939x; 1.0785x over previous
//
#include <hip/hip_runtime.h>

#define B_TOT 8192
#define NB    16         // batch elements per block
#define NPCS  20

typedef __attribute__((ext_vector_type(8))) __fp16 f16x8;
typedef __attribute__((ext_vector_type(4))) float f32x4;
typedef __attribute__((ext_vector_type(2))) __fp16 fp16x2;

__device__ __forceinline__ unsigned pkmax(unsigned a, unsigned b) {
    unsigned d; asm("v_pk_max_f16 %0, %1, %2" : "=v"(d) : "v"(a), "v"(b)); return d;
}
__device__ __forceinline__ unsigned pkmin(unsigned a, unsigned b) {
    unsigned d; asm("v_pk_min_f16 %0, %1, %2" : "=v"(d) : "v"(a), "v"(b)); return d;
}
// RNE f16 pack via compiler-generated casts (default FP rounding = RNE)
__device__ __forceinline__ unsigned pkrne(float a, float b) {
    fp16x2 h;
    h.x = (__fp16)a;
    h.y = (__fp16)b;
    return __builtin_bit_cast(unsigned, h);
}
// RTZ packed cvt (single instruction) — used for h2/x staging (feeds
// sign-random reductions, so truncation bias cancels statistically)
__device__ __forceinline__ unsigned pkrtz(float a, float b) {
    return __builtin_bit_cast(unsigned, __builtin_amdgcn_cvt_pkrtz(a, b));
}
__device__ __forceinline__ float asf(unsigned u) { return __builtin_bit_cast(float, u); }
__device__ __forceinline__ unsigned asu(float f) { return __builtin_bit_cast(unsigned, f); }
__device__ __forceinline__ fp16x2 ash2(unsigned u) { return __builtin_bit_cast(fp16x2, u); }
__device__ __forceinline__ unsigned asu2(fp16x2 h) { return __builtin_bit_cast(unsigned, h); }

// lane-xor exchange within 16-lane DPP rows; lm constant-folded in unrolled loops.
template<int CTRL>
__device__ __forceinline__ unsigned dppmov(unsigned v) {
    return (unsigned)__builtin_amdgcn_mov_dpp((int)v, CTRL, 0xf, 0xf, true);
}
__device__ __forceinline__ unsigned xlane(unsigned v, int lm) {
    switch (lm) {
    case 1:  return dppmov<0xB1>(v);    // quad_perm [1,0,3,2]  = xor 1
    case 2:  return dppmov<0x4E>(v);    // quad_perm [2,3,0,1]  = xor 2
    case 4:  return (unsigned)__builtin_amdgcn_ds_swizzle((int)v, 0x101F); // xor 4
    default: return dppmov<0x128>(v);   // row_ror:8 == xor 8 within 16-lane row
    }
}
__device__ __forceinline__ float xlanef(float v, int lm) { return asf(xlane(asu(v), lm)); }

// ---------------- d_ws layout (bytes) ----------------
// [0,     32768): W2T f16 [128][128]   w2t[j*128+k] = f16(W2[k][pi(j)])  (pi = bit shuffle)
// [32768, 40960): W3T f16 [32][128]    w3t[c*128+k] = f16(W3[k][c])
// [40960, 57344): wsp f32  [32][128]   precomputed fspool weights
// [57344, 61440): w1a u32 [8 ht][64 lane][2]  GEMM1 A-frag pairs (sigma-permuted W1 cols,
//                 zeros for quad!=0 lanes and k>=4 slots)
// [61440, 63488): b1f u32 [8 ht][64 lane]     A-frag k=4 slot: pack(b1[sigma],0) quad0 else 0
#define WS_W3T 32768
#define WS_WSP 40960
#define WS_W1A 57344
#define WS_B1F 61440

__device__ __forceinline__ unsigned packh2(float lo, float hi) {
    unsigned short a = __builtin_bit_cast(unsigned short, (__fp16)lo);
    unsigned short b = __builtin_bit_cast(unsigned short, (__fp16)hi);
    return (unsigned)a | ((unsigned)b << 16);
}

// pi(j) == sigma(n): bit shuffle out[6:5]=in[6:5] out[4:3]=in[3:2] out[2]=in[4] out[1:0]=in[1:0]
// Used (a) to relabel GEMM2 output rows (baked into W2 cols), and (b) to relabel
// GEMM1's MFMA-D rows -> logical h1 (baked into W1 cols + b1), so a1 is a pure
// register rename of GEMM1's D.  Same structural mismatch -> same permutation.
__device__ __forceinline__ int piperm(int j) {
    return (j & 0x60) | ((j & 0x0C) << 1) | ((j & 0x10) >> 2) | (j & 3);
}

__global__ void prep_kernel(const float* __restrict__ W1, const float* __restrict__ b1,
                            const float* __restrict__ W2, const float* __restrict__ W3,
                            const float* __restrict__ pw, void* __restrict__ ws)
{
    const int t = blockIdx.x * 256 + threadIdx.x;
    __fp16* w2t = (__fp16*)ws;
    __fp16* w3t = (__fp16*)((char*)ws + WS_W3T);
    float* wsp  = (float*)((char*)ws + WS_WSP);
    unsigned* w1a = (unsigned*)((char*)ws + WS_W1A);
    unsigned* b1f = (unsigned*)((char*)ws + WS_B1F);
    if (t < 16384) {
        int j = t >> 7, k = t & 127;
        w2t[t] = (__fp16)W2[k * 128 + piperm(j)];
    } else if (t < 20480) {
        int o = t - 16384, c = o >> 7, k = o & 127;
        w3t[o] = (__fp16)W3[k * 32 + c];
    } else if (t < 24576) {
        int o = t - 20480, c = o >> 7, p = o & 127;
        float pos = (float)p * (20.0f / 127.0f);
        int ip = min((int)pos, NPCS);
        float fr = pos - (float)ip;
        int ipb = min(ip + 1, NPCS);
        wsp[o] = (1.0f - fr) * pw[c * 21 + ip] + fr * pw[c * 21 + ipb];
    } else if (t < 25600) {
        // w1a[ht][lane][pair]: A[row=16ht+l16][k=2pair,2pair+1] = W1[k][sigma(row)]
        int idx = t - 24576;
        int ht = idx >> 7, lane = (idx >> 1) & 63, pair = idx & 1;
        int quad = lane >> 4, l16 = lane & 15;
        unsigned val = 0;
        if (quad == 0) {
            int sh = piperm(16 * ht + l16);
            val = packh2(W1[(2 * pair) * 128 + sh], W1[(2 * pair + 1) * 128 + sh]);
        }
        w1a[idx] = val;
    } else if (t < 26112) {
        // b1f[ht][lane]: A k=4 slot carries b1 (multiplied by B k=4 == 1.0)
        int idx = t - 25600;
        int ht = idx >> 6, lane = idx & 63;
        int quad = lane >> 4, l16 = lane & 15;
        unsigned val = 0;
        if (quad == 0) {
            int sh = piperm(16 * ht + l16);
            val = packh2(b1[sh], 0.0f);
        }
        b1f[idx] = val;
    }
}

// ---------------- LDS layout (bytes, total 43264) ----------------
// [0,     32768): sW2T f16, rows 256 B, chunk phys = ch ^ (row&15)  (xor swizzle)
// [32768, 41216): szp  uint [16][132]  packed-f16 z pairs
// [41216, 43264): spool f32[NB*32] = 2048 B  (NB=16)
#define L_SZP  32768
#define L_POOL 41216

__global__ __launch_bounds__(256, 2) void enc_kernel(
    const float* __restrict__ x,   const float* __restrict__ b1g,
    const float* __restrict__ b2g, const float* __restrict__ b3g,
    const float* __restrict__ eps, const void* __restrict__ ws,
    float* __restrict__ out)
{
    __shared__ __align__(16) char smem[43264];

    const int tid  = threadIdx.x;
    const int wv   = tid >> 6;
    const int lane = tid & 63;
    const int l16  = lane & 15;     // lane-within-group for the sort
    const int quad = lane >> 4;
    const int b0   = blockIdx.x * NB;

    // ---------- stage sW2T (xor-swizzled) ----------
    {
        const uint4* src = (const uint4*)ws;     // 2048 16B chunks
#pragma unroll
        for (int it = 0; it < 8; ++it) {
            int idx = tid + it * 256;
            int j = idx >> 4, ch = idx & 15;
            *(uint4*)(smem + j * 256 + ((ch ^ (j & 15)) * 16)) = src[idx];
        }
    }

    // ---------- hoisted register-resident data (persist across NB elements) ----------
    f16x8 w3f[2][4];                                   // W3T A-frags
    {
        const __fp16* w3t = (const __fp16*)((const char*)ws + WS_W3T);
#pragma unroll
        for (int mt2 = 0; mt2 < 2; ++mt2)
#pragma unroll
            for (int kt = 0; kt < 4; ++kt)
                w3f[mt2][kt] = *(const f16x8*)(w3t + (mt2 * 16 + l16) * 128 + kt * 32 + quad * 8);
    }
    // GEMM1 A-frags (W1 sigma-permuted, k4 = b1, rest zero) — element-invariant
    union WF { unsigned u[4]; f16x8 v; } w1f[8];
    {
        const unsigned* w1a = (const unsigned*)((const char*)ws + WS_W1A);
        const unsigned* b1f = (const unsigned*)((const char*)ws + WS_B1F);
#pragma unroll
        for (int ht = 0; ht < 8; ++ht) {
            uint2 w01 = *(const uint2*)(w1a + ht * 128 + lane * 2);
            w1f[ht].u[0] = w01.x;
            w1f[ht].u[1] = w01.y;
            w1f[ht].u[2] = b1f[ht * 64 + lane];
            w1f[ht].u[3] = 0;
        }
    }
    // persistent MFMA bias seeds (C operand of first-kt MFMA; D != C so never clobbered)
    f32x4 b3acc[2];
    {
        float4 t0 = *(const float4*)(b3g + quad * 4);
        float4 t1 = *(const float4*)(b3g + 16 + quad * 4);
        b3acc[0] = (f32x4){t0.x, t0.y, t0.z, t0.w};
        b3acc[1] = (f32x4){t1.x, t1.y, t1.z, t1.w};
    }
    // swapped-GEMM2 D rows = h (pi-ordered): C-seed b2[pi(nt*16+quad*4+r)]
    f32x4 b2acc[8];
#pragma unroll
    for (int nt = 0; nt < 8; ++nt) {
        float4 t4 = *(const float4*)(b2g + (nt >> 1) * 32 + quad * 8 + (nt & 1) * 4);
        b2acc[nt] = (f32x4){t4.x, t4.y, t4.z, t4.w};
    }

    // fspool weights for this lane's pair-row (element-invariant)
    const int pr = wv * 4 + quad;    // packed pair-row: channels 2pr (mu), 2pr+1 (logvar)
    float wE[8], wO[8];
    {
        const float* wsp = (const float*)((const char*)ws + WS_WSP);
        float4 e0 = *(const float4*)(wsp + (2 * pr) * 128 + l16 * 8);
        float4 e1 = *(const float4*)(wsp + (2 * pr) * 128 + l16 * 8 + 4);
        float4 o0 = *(const float4*)(wsp + (2 * pr + 1) * 128 + l16 * 8);
        float4 o1 = *(const float4*)(wsp + (2 * pr + 1) * 128 + l16 * 8 + 4);
        wE[0]=e0.x; wE[1]=e0.y; wE[2]=e0.z; wE[3]=e0.w; wE[4]=e1.x; wE[5]=e1.y; wE[6]=e1.z; wE[7]=e1.w;
        wO[0]=o0.x; wO[1]=o0.y; wO[2]=o0.z; wO[3]=o0.w; wO[4]=o1.x; wO[5]=o1.y; wO[6]=o1.z; wO[7]=o1.w;
    }

    // sort sign-flip masks (per k-stage, lane-dependent, element-invariant)
    const int ib = l16 * 8;
    const unsigned sfl8  = (ib & 8)  ? 0x80008000u : 0u;
    const unsigned sfl16 = (ib & 16) ? 0x80008000u : 0u;
    const unsigned sfl32 = (ib & 32) ? 0x80008000u : 0u;
    const unsigned sfl64 = (ib & 64) ? 0x80008000u : 0u;

    __syncthreads();

    unsigned* szp   = (unsigned*)(smem + L_SZP);       // stride 132
    float*    spool = (float*)(smem + L_POOL);

    // GEMM1 B-frags: u[0,1] = x k0..3 (per element); u[2] = {1.0,1.0} (k4 bias lane;
    // k5 multiplied by A=0); u[3] = 0.  A's zeros kill k>=5 and quad!=0 garbage.
    union XB { unsigned u[4]; f16x8 v; } xb0, xb1;
    xb0.u[2] = 0x3C003C00u; xb0.u[3] = 0;
    xb1.u[2] = 0x3C003C00u; xb1.u[3] = 0;
    const f32x4 zc = (f32x4){0.f, 0.f, 0.f, 0.f};

    // x prefetch: element 0 loaded ahead of the loop
    const float* xptr = x + (size_t)b0 * 512 + (wv * 32 + l16) * 4;
    float4 xv0 = *(const float4*)(xptr);
    float4 xv1 = *(const float4*)(xptr + 64);

    for (int e = 0; e < NB; ++e) {
        // ---------- GEMM1 (MFMA, K=32 with k0..3 = x, k4 = bias): h1 = relu(x@W1+b1) ----------
        xb0.u[0] = pkrtz(xv0.x, xv0.y);
        xb0.u[1] = pkrtz(xv0.z, xv0.w);
        xb1.u[0] = pkrtz(xv1.x, xv1.y);
        xb1.u[1] = pkrtz(xv1.z, xv1.w);

        // prefetch next element's x (consumed next iteration; hides HBM latency)
        if (e + 1 < NB) {
            xv0 = *(const float4*)(xptr + (e + 1) * 512);
            xv1 = *(const float4*)(xptr + (e + 1) * 512 + 64);
        }

        // D rows n = 16ht+4quad+r hold h1[sigma(n)]; relu+pack lands each value at
        // a1[ht>>1].u[2*(ht&1)+(r>=2)], which is exactly B-frag k-slot sigma(n).
        union AF { unsigned u[4]; f16x8 v; } a1[2][4];
#pragma unroll
        for (int ht = 0; ht < 8; ++ht) {
            f32x4 d0 = __builtin_amdgcn_mfma_f32_16x16x32_f16(w1f[ht].v, xb0.v, zc, 0, 0, 0);
            f32x4 d1 = __builtin_amdgcn_mfma_f32_16x16x32_f16(w1f[ht].v, xb1.v, zc, 0, 0, 0);
            const int kt = ht >> 1, jb = 2 * (ht & 1);
            a1[0][kt].u[jb]     = pkmax(pkrtz(d0[0], d0[1]), 0u);
            a1[0][kt].u[jb + 1] = pkmax(pkrtz(d0[2], d0[3]), 0u);
            a1[1][kt].u[jb]     = pkmax(pkrtz(d1[0], d1[1]), 0u);
            a1[1][kt].u[jb + 1] = pkmax(pkrtz(d1[2], d1[3]), 0u);
        }

        // ---------- GEMM2 (MFMA f16, SWAPPED): D = W2T-frag . h1-frag, rows=h cols=p ----------
        f32x4 acc2[2][8];
#pragma unroll
        for (int kt = 0; kt < 4; ++kt)
#pragma unroll
            for (int nt = 0; nt < 8; ++nt) {
                const int j = nt * 16 + l16;
                const int phys = (kt * 4 + quad) ^ l16;
                f16x8 wf = *(const f16x8*)(smem + j * 256 + phys * 16);
                if (kt == 0) {
                    acc2[0][nt] = __builtin_amdgcn_mfma_f32_16x16x32_f16(wf, a1[0][0].v, b2acc[nt], 0, 0, 0);
                    acc2[1][nt] = __builtin_amdgcn_mfma_f32_16x16x32_f16(wf, a1[1][0].v, b2acc[nt], 0, 0, 0);
                } else {
                    acc2[0][nt] = __builtin_amdgcn_mfma_f32_16x16x32_f16(wf, a1[0][kt].v, acc2[0][nt], 0, 0, 0);
                    acc2[1][nt] = __builtin_amdgcn_mfma_f32_16x16x32_f16(wf, a1[1][kt].v, acc2[1][nt], 0, 0, 0);
                }
            }

        // ---------- GEMM3: z = W3T @ h2^T (+b3); B-frag = in-register repack (pi magic) ----------
#pragma unroll
        for (int mt = 0; mt < 2; ++mt) {
            // relu + packed-f16: pk[nt] holds h pairs {pi-base, +1} and {+2, +3}
            unsigned pkx[8], pky[8];
#pragma unroll
            for (int nt = 0; nt < 8; ++nt) {
                pkx[nt] = pkmax(pkrtz(acc2[mt][nt][0], acc2[mt][nt][1]), 0u);
                pky[nt] = pkmax(pkrtz(acc2[mt][nt][2], acc2[mt][nt][3]), 0u);
            }
            // a3[kt] k-elems quad*8+{0..7} == pk[2kt],pk[2kt+1] by pi construction
            union A3 { unsigned u[4]; f16x8 v; } a3[4];
#pragma unroll
            for (int kt = 0; kt < 4; ++kt) {
                a3[kt].u[0] = pkx[2 * kt];
                a3[kt].u[1] = pky[2 * kt];
                a3[kt].u[2] = pkx[2 * kt + 1];
                a3[kt].u[3] = pky[2 * kt + 1];
            }

            const int colbase = wv * 32 + mt * 16;
#pragma unroll
            for (int mt2 = 0; mt2 < 2; ++mt2) {
                f32x4 acc = __builtin_amdgcn_mfma_f32_16x16x32_f16(w3f[mt2][0], a3[0].v, b3acc[mt2], 0, 0, 0);
#pragma unroll
                for (int kt = 1; kt < 4; ++kt)
                    acc = __builtin_amdgcn_mfma_f32_16x16x32_f16(w3f[mt2][kt], a3[kt].v, acc, 0, 0, 0);
                // lane holds z rows c = 16*mt2 + 4*quad + r, col p = colbase + l16
                const int prw = 8 * mt2 + 2 * quad;
                szp[prw * 132 + colbase + l16]       = pkrne(acc[0], acc[1]);  // RNE; lo=even c (mu)
                szp[(prw + 1) * 132 + colbase + l16] = pkrne(acc[2], acc[3]);
            }
        }
        __syncthreads();  // all waves' z columns visible

        // ---------- packed-f16 bitonic sort, 8 elems/lane over 16-lane groups ----------
        // group = quad; virtual element index i = l16*8 + r; full sort => input order free
        unsigned v[8];
        {
            const unsigned* zp = szp + pr * 132 + l16 * 8;
            uint4 za = *(const uint4*)zp;
            uint4 zb = *(const uint4*)(zp + 4);
            v[0]=za.x; v[1]=za.y; v[2]=za.z; v[3]=za.w;
            v[4]=zb.x; v[5]=zb.y; v[6]=zb.z; v[7]=zb.w;
        }
#pragma unroll
        for (int k = 2; k <= 128; k <<= 1) {
#pragma unroll
            for (int j = 64; j >= 1; j >>= 1) {
                if (j >= k) continue;
                if (j >= 8) {                       // cross-lane (within 16-lane DPP row)
                    const bool km = ((ib & k) == 0) != ((ib & j) != 0);
                    const int lm = j >> 3;
#pragma unroll
                    for (int r = 0; r < 8; ++r) {
                        unsigned p = xlane(v[r], lm);
                        unsigned mx = pkmax(v[r], p), mn = pkmin(v[r], p);
                        v[r] = km ? mx : mn;
                    }
                } else if (k <= 4) {                // in-lane, static direction
#pragma unroll
                    for (int a = 0; a < 8; ++a) {
                        if (a & j) continue;
                        const int bx = a | j;
                        unsigned mx = pkmax(v[a], v[bx]), mn = pkmin(v[a], v[bx]);
                        if ((a & k) == 0) { v[a] = mx; v[bx] = mn; }
                        else              { v[a] = mn; v[bx] = mx; }
                    }
                } else {                            // k>=8, j<=4: sign-flip -> static descending
                    const unsigned sfl = (k == 8) ? sfl8 : (k == 16) ? sfl16 :
                                         (k == 32) ? sfl32 : (k == 64) ? sfl64 : 0u;
                    if (j == 4 && k != 128) {
#pragma unroll
                        for (int r = 0; r < 8; ++r) v[r] ^= sfl;
                    }
#pragma unroll
                    for (int a = 0; a < 8; ++a) {
                        if (a & j) continue;
                        const int bx = a | j;
                        unsigned mx = pkmax(v[a], v[bx]), mn = pkmin(v[a], v[bx]);
                        v[a] = mx; v[bx] = mn;
                    }
                    if (j == 1 && k != 128) {
#pragma unroll
                        for (int r = 0; r < 8; ++r) v[r] ^= sfl;
                    }
                }
            }
        }

        // ---------- weighted sum + 16-lane group reduction (DPP) ----------
        float sE = 0.f, sO = 0.f;
#pragma unroll
        for (int r = 0; r < 8; ++r) {
            const fp16x2 hv = ash2(v[r]);
            sE = fmaf(wE[r], (float)hv.x, sE);
            sO = fmaf(wO[r], (float)hv.y, sO);
        }
#pragma unroll
        for (int d = 8; d >= 1; d >>= 1) {
            sE += xlanef(sE, d);
            sO += xlanef(sO, d);
        }
        if (l16 == 0) {
            spool[e * 32 + 2 * pr]     = sE;
            spool[e * 32 + 2 * pr + 1] = sO;
        }
        __syncthreads();  // spool ready; protects szp WAR for next element
    }

    // ---------- batched coalesced epilogue (NB*16 == 256) ----------
    {
        const int e = tid >> 4, t = tid & 15;
        const float mu = spool[e * 32 + 2 * t];
        const float lv = spool[e * 32 + 2 * t + 1];
        const float ev = eps[(size_t)b0 * 16 + tid];
        const float smp = fmaf(ev, __expf(0.5f * lv), mu);
        out[(size_t)b0 * 16 + tid] = mu;
        out[(size_t)B_TOT * 16 + (size_t)b0 * 16 + tid] = lv;
        out[(size_t)2 * B_TOT * 16 + (size_t)b0 * 16 + tid] = smp;
    }
}

extern "C" void kernel_launch(void* const* d_in, const int* in_sizes, int n_in,
                              void* d_out, int out_size, void* d_ws, size_t ws_size,
                              hipStream_t stream) {
    const float* x   = (const float*)d_in[0];
    const float* W1  = (const float*)d_in[1];
    const float* b1  = (const float*)d_in[2];
    const float* W2  = (const float*)d_in[3];
    const float* b2  = (const float*)d_in[4];
    const float* W3  = (const float*)d_in[5];
    const float* b3  = (const float*)d_in[6];
    const float* pw  = (const float*)d_in[7];
    const float* eps = (const float*)d_in[8];
    float* out = (float*)d_out;

    prep_kernel<<<dim3(102), dim3(256), 0, stream>>>(W1, b1, W2, W3, pw, d_ws);
    enc_kernel<<<dim3(B_TOT / NB), dim3(256), 0, stream>>>(x, b1, b2, b3, eps, d_ws, out);
}